// Round 6
// baseline (430.501 us; speedup 1.0000x reference)
//
#include <hip/hip_runtime.h>
#include <cstdint>
#include <type_traits>

typedef unsigned short u16;
typedef unsigned int u32;
typedef __bf16 bf16x8 __attribute__((ext_vector_type(8)));
typedef float f32x4 __attribute__((ext_vector_type(4)));

constexpr int BB = 2;
constexpr int SEQ = 2048;
constexpr int CH = 2048;
constexpr int NH = 16;
constexpr int NKV = 4;
constexpr int HD = 128;
constexpr int QKVC = CH + 2 * NKV * HD;  // 3072

#define DI __device__ __forceinline__

DI u16 f2b(float x) {  // fp32 -> bf16 bits, RNE
  u32 u = __float_as_uint(x);
  u = u + 0x7FFFu + ((u >> 16) & 1u);
  return (u16)(u >> 16);
}
DI float b2f(u16 u) { return __uint_as_float(((u32)u) << 16); }

// pack two fp32 -> two bf16 (truncating) in ONE v_perm_b32
DI u32 pack2bf(float lo, float hi) {
  return __builtin_amdgcn_perm(__float_as_uint(hi), __float_as_uint(lo), 0x07060302u);
}

// async global->LDS, 16B per lane. LDS dest is wave-uniform base + lane*16.
DI void glds16(const void* g, void* l) {
  __builtin_amdgcn_global_load_lds(
      (__attribute__((address_space(1))) void*)(uintptr_t)g,
      (__attribute__((address_space(3))) void*)(u32)(uintptr_t)l, 16, 0, 0);
}

// ---------------- elementwise fp32 -> bf16 ----------------
__global__ __launch_bounds__(256) void xconv_kernel(const float* __restrict__ in,
                                                    u16* __restrict__ out, int n4) {
  int i = blockIdx.x * 256 + threadIdx.x;
  if (i < n4) {
    float4 v = *(const float4*)&in[(size_t)i * 4];
    ushort4 o;
    o.x = f2b(v.x); o.y = f2b(v.y); o.z = f2b(v.z); o.w = f2b(v.w);
    *(ushort4*)&out[(size_t)i * 4] = o;
  }
}

// ------- transpose-convert all 4 weights fp32 (2048 x Cc) -> bf16 (Cc x 2048) -------
__global__ __launch_bounds__(256) void wtrans4_kernel(
    const float* __restrict__ Wq, const float* __restrict__ Wk,
    const float* __restrict__ Wv, const float* __restrict__ Wo,
    u16* __restrict__ wqkvt, u16* __restrict__ wot) {
  const int z = blockIdx.z;
  const float* in;
  u16* out;
  int Cc;
  if (z == 0)      { in = Wq; out = wqkvt;                                Cc = CH; }
  else if (z == 1) { in = Wk; out = wqkvt + (size_t)CH * CH;              Cc = NKV * HD; }
  else if (z == 2) { in = Wv; out = wqkvt + (size_t)(CH + NKV * HD) * CH; Cc = NKV * HD; }
  else             { in = Wo; out = wot;                                  Cc = CH; }
  if ((int)blockIdx.y * 64 >= Cc) return;

  __shared__ u16 tile[64 * 65];
  const int r0 = blockIdx.x * 64, c0 = blockIdx.y * 64;
  const int tid = threadIdx.x;
  for (int c = tid; c < 1024; c += 256) {
    int r = c >> 4, col = (c & 15) * 4;
    float4 v = *(const float4*)&in[(size_t)(r0 + r) * Cc + c0 + col];
    tile[r * 65 + col + 0] = f2b(v.x);
    tile[r * 65 + col + 1] = f2b(v.y);
    tile[r * 65 + col + 2] = f2b(v.z);
    tile[r * 65 + col + 3] = f2b(v.w);
  }
  __syncthreads();
  for (int c = tid; c < 1024; c += 256) {
    int r = c >> 4, col = (c & 15) * 4;
    ushort4 v;
    v.x = tile[(col + 0) * 65 + r];
    v.y = tile[(col + 1) * 65 + r];
    v.z = tile[(col + 2) * 65 + r];
    v.w = tile[(col + 3) * 65 + r];
    *(ushort4*)&out[(size_t)(c0 + r) * CH + r0 + col] = v;
  }
}

// ------------- transpose bf16 V (SEQ x HD slices) -> V^T (HD x SEQ) -------------
// With flash-LDS kv-slot bit-permutation (w0..w5 = u0,u1,u5,u2,u3,u4) and
// XOR-16B-group swizzle (gl ^= d&7) folded into the output layout.
__global__ __launch_bounds__(256) void vtrans_kernel(const u16* __restrict__ in,
                                                     u16* __restrict__ out) {
  __shared__ u16 tile[64 * 65];
  const int s = blockIdx.z, n0 = blockIdx.x * 64, d0 = blockIdx.y * 64;
  const int tid = threadIdx.x;
  const u16* ip = in + (size_t)s * SEQ * HD + (size_t)n0 * HD + d0;
  u16* op = out + (size_t)s * HD * SEQ + (size_t)d0 * SEQ + n0;
  for (int c = tid; c < 1024; c += 256) {
    int r = c >> 4, col = (c & 15) * 4;
    ushort4 v = *(const ushort4*)&ip[(size_t)r * HD + col];
    tile[r * 65 + col + 0] = v.x;
    tile[r * 65 + col + 1] = v.y;
    tile[r * 65 + col + 2] = v.z;
    tile[r * 65 + col + 3] = v.w;
  }
  __syncthreads();
  for (int c = tid; c < 1024; c += 256) {
    int r = c >> 4, col = (c & 15) * 4;  // r = local d, col = local n (u), u&3==0
    ushort4 v;
    v.x = tile[(col + 0) * 65 + r];
    v.y = tile[(col + 1) * 65 + r];
    v.z = tile[(col + 2) * 65 + r];
    v.w = tile[(col + 3) * 65 + r];
    int u = col;
    int w = (u & 3) | (((u >> 5) & 1) << 2) | (((u >> 2) & 3) << 3) | (((u >> 4) & 1) << 5);
    int glp = (w >> 3) ^ (r & 7);
    int colp = glp * 8 + (w & 7);
    *(ushort4*)&op[(size_t)r * SEQ + colp] = v;
  }
}

// ---------------- bf16 MFMA GEMM, BK=64 (32 MFMAs per barrier-pair) ----------------
// C[M,Nn] = A[M,K] @ Bt[Nn,K]^T.  MODE 0: bf16 out + qkv bias, V columns routed
// directly to Vn[(b,kv,n,d)]. MODE 1: fp32 out.
// LDS rows hold 64 cols (128 B); 16B slot s of row r holds global col-group
// s^(r&7) (XOR swizzle on the GLOBAL side -- glds16 LDS side must stay
// base+lane*16). Readers use slot (cg)^(lm&7) -> banks spread over all 8 groups.
template <int MODE>
__global__ __launch_bounds__(256, 3) void gemm_kernel(
    const u16* __restrict__ A, const u16* __restrict__ Bt,
    u16* __restrict__ Cb, float* __restrict__ Cf, u16* __restrict__ Vn,
    const float* __restrict__ bq, const float* __restrict__ bk,
    const float* __restrict__ bv, int M, int Nn, int K) {
  __shared__ u16 As[128 * 64];
  __shared__ u16 Bs[128 * 64];
  const int tid = threadIdx.x;
  const int lane = tid & 63, wave = tid >> 6;
  const int wrow = wave >> 1, wcol = wave & 1;  // 2x2 waves of 64x64
  const int m0 = blockIdx.x * 128, n0 = blockIdx.y * 128;
  const int lm = lane & 15, lq = lane >> 4;
  f32x4 acc[4][4] = {};

  const int grow = tid >> 3;                          // staging row 0..31 (+c*32)
  const int gcol = ((lane & 7) ^ (lane >> 3)) * 8;    // swizzled global col
  const u16* ag = A + (size_t)(m0 + grow) * K + gcol;
  const u16* bg = Bt + (size_t)(n0 + grow) * K + gcol;
  char* asb = (char*)As + wave * 1024;  // wave-uniform LDS base (+c*4096)
  char* bsb = (char*)Bs + wave * 1024;
  const size_t rowskip = (size_t)32 * K;

  for (int k = 0; k < K; k += 64) {
    __syncthreads();
#pragma unroll
    for (int c = 0; c < 4; c++) {
      glds16(ag + c * rowskip + k, asb + c * 4096);
      glds16(bg + c * rowskip + k, bsb + c * 4096);
    }
    __syncthreads();  // vmcnt(0) drain -> tile staged
#pragma unroll
    for (int kk = 0; kk < 2; kk++) {
      bf16x8 af[4], bfr[4];
      const int slot = ((kk * 4 + lq) ^ (lm & 7)) * 16;
#pragma unroll
      for (int i = 0; i < 4; i++)
        af[i] = *(const bf16x8*)((const char*)As + (wrow * 64 + i * 16 + lm) * 128 + slot);
#pragma unroll
      for (int j = 0; j < 4; j++)
        bfr[j] = *(const bf16x8*)((const char*)Bs + (wcol * 64 + j * 16 + lm) * 128 + slot);
#pragma unroll
      for (int i = 0; i < 4; i++)
#pragma unroll
        for (int j = 0; j < 4; j++)
          acc[i][j] = __builtin_amdgcn_mfma_f32_16x16x32_bf16(af[i], bfr[j], acc[i][j], 0, 0, 0);
    }
  }

#pragma unroll
  for (int i = 0; i < 4; i++) {
    const int mg = m0 + wrow * 64 + i * 16 + lq * 4;
#pragma unroll
    for (int j = 0; j < 4; j++) {
      const int ng = n0 + wcol * 64 + j * 16 + lm;
      float bias = 0.f;
      if (MODE == 0)
        bias = (ng < CH) ? bq[ng] : (ng < CH + NKV * HD ? bk[ng - CH] : bv[ng - CH - NKV * HD]);
#pragma unroll
      for (int r = 0; r < 4; r++) {
        float v = acc[i][j][r] + bias;
        if (MODE == 0) {
          if (ng >= CH + NKV * HD) {  // V: route straight to (b,kv,n,d) layout
            int tok = mg + r;
            int bidx = tok >> 11, n = tok & (SEQ - 1);
            int vcol = ng - (CH + NKV * HD);
            int kh = vcol >> 7, d = vcol & (HD - 1);
            Vn[((size_t)(bidx * NKV + kh) * SEQ + n) * HD + d] = f2b(v);
          } else {
            Cb[(size_t)(mg + r) * Nn + ng] = f2b(v);
          }
        } else {
          Cf[(size_t)(mg + r) * Nn + ng] = v;
        }
      }
    }
  }
}

// ---------------- RoPE (interleaved), Q + K only ----------------
__global__ __launch_bounds__(256) void rope_kernel(
    const u16* __restrict__ qkv, const int* __restrict__ pos,
    u16* __restrict__ Qo, u16* __restrict__ Ko) {
  __shared__ float cs_s[64], sn_s[64];
  const int tok = blockIdx.x;
  const int b = tok >> 11, n = tok & (SEQ - 1);
  const int t = threadIdx.x;
  const u16* row = qkv + (size_t)tok * QKVC;
  const float LN1E4_64 = 0.14391156831212788f;  // ln(10000)/64

  if (t < 64) {
    float ang = (float)pos[tok] * expf(-(float)t * LN1E4_64);
    float sn, cs;
    sincosf(ang, &sn, &cs);
    cs_s[t] = cs;
    sn_s[t] = sn;
  }
  __syncthreads();

  for (int idx = t; idx < NH * 64; idx += 256) {  // q: 1024 pairs
    int hh = idx >> 6, i = idx & 63;
    float cs = cs_s[i], sn = sn_s[i];
    float q0v = b2f(row[hh * 128 + 2 * i]);
    float q1v = b2f(row[hh * 128 + 2 * i + 1]);
    size_t off = ((size_t)(b * NH + hh) * SEQ + n) * HD + 2 * i;
    Qo[off] = f2b(q0v * cs - q1v * sn);
    Qo[off + 1] = f2b(q1v * cs + q0v * sn);
  }
  {  // k: 256 pairs, one per thread, swizzled store
    int kh = t >> 6, i = t & 63;
    float cs = cs_s[i], sn = sn_s[i];
    float k0v = b2f(row[CH + kh * 128 + 2 * i]);
    float k1v = b2f(row[CH + kh * 128 + 2 * i + 1]);
    int d0 = 2 * i;
    int g = d0 >> 3;
    int gp = (g & 8) | ((g ^ n) & 7);
    int dp = gp * 8 + (d0 & 7);
    size_t off = ((size_t)(b * NKV + kh) * SEQ + n) * HD + dp;
    Ko[off] = f2b(k0v * cs - k1v * sn);
    Ko[off + 1] = f2b(k1v * cs + k0v * sn);
  }
}

// ---------------- causal GQA flash attention (v6: 4 q-tiles/wave) ----------------
// Block p in 0..7 handles q-tiles {31-p, 16+p, 15-p, p} (constant 66 work units).
// 256 blocks = 1/CU, 4 waves, launch_bounds(256,1) -> ~512-VGPR budget, so the
// 4x fragment state (oacc 128 + qf 64 + sv 64 + oaccS 16) fits without spill.
// Each kf/vf LDS read now feeds 4 MFMAs -> per-wave LDS tile traffic amortized
// over 64 q-rows (was 32). Tiles deactivate in index order as t grows.
__global__ __launch_bounds__(256, 1) void flash_kernel(
    const u16* __restrict__ Q, const u16* __restrict__ Kk,
    const u16* __restrict__ Vt, u16* __restrict__ Oo) {
  __shared__ u16 Kb[2][64 * 128];    // [kv][d-swizzled]
  __shared__ u16 Vb[2][144 * 64];    // [d][kv-permuted-swizzled]; row 128 = ones
  const int tid = threadIdx.x, lane = tid & 63, wave = tid >> 6;
  const int lm = lane & 15, lq = lane >> 4;
  const int p = blockIdx.x;  // 0..7
  const int h = blockIdx.y, b = blockIdx.z;
  const int q0s[4] = {(31 - p) * 64, (16 + p) * 64, (15 - p) * 64, p * 64};
  const int kvh = h >> 2;  // groups = H/KV = 4
  const u16* Qg = Q + (size_t)(b * NH + h) * SEQ * HD;
  const u16* Kg = Kk + (size_t)(b * NKV + kvh) * SEQ * HD;
  const u16* Vg = Vt + (size_t)(b * NKV + kvh) * HD * SEQ;  // [HD][SEQ]

  if (tid < 128) Vb[tid >> 6][128 * 64 + (tid & 63)] = 0x3F80;  // bf16 1.0 ones-row

  // loop-invariant Q fragments (B-operand: lane holds Q[q=lm][k=lq*8+j])
  bf16x8 qf[4][4];
#pragma unroll
  for (int tu = 0; tu < 4; tu++) {
    const u16* qrow = Qg + (size_t)(q0s[tu] + wave * 16 + lm) * HD;
#pragma unroll
    for (int kd = 0; kd < 4; kd++)
      qf[tu][kd] = *(const bf16x8*)&qrow[kd * 32 + lq * 8];
  }

  f32x4 oacc[4][8] = {};
  f32x4 oaccS[4] = {};             // ones-column: row-sums of P
  const float SCL2 = 0.12754325f;  // (1/sqrt(128)) * log2(e)
  const int nIter = 32 - p;

  auto stage = [&](int kv0, int bufi) {
    const char* kb = (const char*)(Kg + (size_t)kv0 * HD);
    char* kl = (char*)&Kb[bufi][0];
    const char* vbb = (const char*)(Vg + (size_t)kv0);
    char* vl = (char*)&Vb[bufi][0];
#pragma unroll
    for (int c = 0; c < 4; c++) {
      int ch = wave * 4 + c;
      glds16(kb + ch * 1024 + lane * 16, kl + ch * 1024);
      glds16(vbb + (size_t)(ch * 8 + (lane >> 3)) * (SEQ * 2) + (lane & 7) * 16,
             vl + ch * 1024);
    }
  };

  stage(0, 0);

  for (int t = 0; t < nIter; t++) {
    __syncthreads();                    // drains vmcnt -> tile t resident
    if (t + 1 < nIter) stage((t + 1) * 64, (t + 1) & 1);  // async behind compute
    const u16* Ks = &Kb[t & 1][0];
    const u16* Vs = &Vb[t & 1][0];
    const int kv0 = t * 64;
    const int na = 1 + (t <= 16 + p) + (t <= 15 - p) + (t <= p);

    auto run = [&](auto nc) {
      constexpr int N = decltype(nc)::value;
      // S^T: lane holds S[q=lm][kv = nt*16 + lq*4 + r] per tile
      f32x4 sv[N][4];
#pragma unroll
      for (int tu = 0; tu < N; tu++)
#pragma unroll
        for (int nt = 0; nt < 4; nt++) sv[tu][nt] = f32x4{0.f, 0.f, 0.f, 0.f};
#pragma unroll
      for (int nt = 0; nt < 4; nt++)
#pragma unroll
        for (int kd = 0; kd < 4; kd++) {
          int g = kd * 4 + lq;
          int gpp = (g & 8) | ((g ^ lm) & 7);
          bf16x8 kf = *(const bf16x8*)&Ks[(nt * 16 + lm) * 128 + gpp * 8];
#pragma unroll
          for (int tu = 0; tu < N; tu++)
            sv[tu][nt] = __builtin_amdgcn_mfma_f32_16x16x32_bf16(kf, qf[tu][kd], sv[tu][nt], 0, 0, 0);
        }

      // p = exp2(s*scale); perm-pack (truncate) into x32 A-frags
      alignas(16) u32 pad[N][2][4];
#pragma unroll
      for (int tu = 0; tu < N; tu++) {
        const int base = q0s[tu] + wave * 16;
        if (kv0 + 63 > base) {  // straddles diagonal
          const int qrow = base + lm;
#pragma unroll
          for (int nt = 0; nt < 4; nt++) {
            float pv[4];
#pragma unroll
            for (int r = 0; r < 4; r++) {
              int kvg = kv0 + nt * 16 + lq * 4 + r;
              float e = exp2f(sv[tu][nt][r] * SCL2);
              pv[r] = (kvg > qrow) ? 0.f : e;
            }
            pad[tu][nt & 1][(nt >> 1) * 2 + 0] = pack2bf(pv[0], pv[1]);
            pad[tu][nt & 1][(nt >> 1) * 2 + 1] = pack2bf(pv[2], pv[3]);
          }
        } else {
#pragma unroll
          for (int nt = 0; nt < 4; nt++) {
            float pv[4];
#pragma unroll
            for (int r = 0; r < 4; r++) pv[r] = exp2f(sv[tu][nt][r] * SCL2);
            pad[tu][nt & 1][(nt >> 1) * 2 + 0] = pack2bf(pv[0], pv[1]);
            pad[tu][nt & 1][(nt >> 1) * 2 + 1] = pack2bf(pv[2], pv[3]);
          }
        }
      }

      // O += P.V  (x32; B-frag = V^T[d][kv] slots, pre-permuted+swizzled)
#pragma unroll
      for (int ks = 0; ks < 2; ks++) {
        const int glp = (ks * 4 + lq) ^ (lm & 7);
#pragma unroll
        for (int dt = 0; dt < 8; dt++) {
          bf16x8 vf = *(const bf16x8*)&Vs[(dt * 16 + lm) * 64 + glp * 8];
#pragma unroll
          for (int tu = 0; tu < N; tu++)
            oacc[tu][dt] = __builtin_amdgcn_mfma_f32_16x16x32_bf16(
                *(const bf16x8*)&pad[tu][ks][0], vf, oacc[tu][dt], 0, 0, 0);
        }
        bf16x8 vf8 = *(const bf16x8*)&Vs[(128 + lm) * 64 + glp * 8];
#pragma unroll
        for (int tu = 0; tu < N; tu++)
          oaccS[tu] = __builtin_amdgcn_mfma_f32_16x16x32_bf16(
              *(const bf16x8*)&pad[tu][ks][0], vf8, oaccS[tu], 0, 0, 0);
      }
    };
    if (na == 4)      run(std::integral_constant<int, 4>{});
    else if (na == 3) run(std::integral_constant<int, 3>{});
    else if (na == 2) run(std::integral_constant<int, 2>{});
    else              run(std::integral_constant<int, 1>{});
  }

  // row m's sum sits at lane (m>>2)*16, reg m&3 of oaccS (C-layout col 128 = lm 0)
  u16* orow = Oo + (size_t)b * SEQ * CH + (size_t)h * HD;
#pragma unroll
  for (int tu = 0; tu < 4; tu++) {
    float inv[4];
#pragma unroll
    for (int r = 0; r < 4; r++) inv[r] = 1.0f / __shfl(oaccS[tu][r], lq * 16);
    const int qrow_base = q0s[tu] + wave * 16 + lq * 4;
#pragma unroll
    for (int dt = 0; dt < 8; dt++)
#pragma unroll
      for (int r = 0; r < 4; r++)
        orow[(size_t)(qrow_base + r) * CH + dt * 16 + lm] = f2b(oacc[tu][dt][r] * inv[r]);
  }
}

extern "C" void kernel_launch(void* const* d_in, const int* in_sizes, int n_in,
                              void* d_out, int out_size, void* d_ws, size_t ws_size,
                              hipStream_t stream) {
  const float* x = (const float*)d_in[0];
  const int* pos = (const int*)d_in[1];
  const float* Wq = (const float*)d_in[2];
  const float* bq = (const float*)d_in[3];
  const float* Wk = (const float*)d_in[4];
  const float* bk = (const float*)d_in[5];
  const float* Wv = (const float*)d_in[6];
  const float* bv = (const float*)d_in[7];
  const float* Wo = (const float*)d_in[8];
  float* out = (float*)d_out;

  char* ws = (char*)d_ws;
  u16* xb = (u16*)ws;    ws += (size_t)BB * SEQ * CH * 2;        // 16.8 MB
  u16* wqkvt = (u16*)ws; ws += (size_t)QKVC * CH * 2;            // 12.6 MB  (3072 x 2048, n-major)
  u16* wot = (u16*)ws;   ws += (size_t)CH * CH * 2;              // 8.4 MB
  u16* qkv = (u16*)ws;   ws += (size_t)BB * SEQ * QKVC * 2;      // 25.2 MB
  u16* qr = (u16*)ws;    ws += (size_t)BB * NH * SEQ * HD * 2;   // 16.8 MB
  u16* kr = (u16*)ws;    ws += (size_t)BB * NKV * SEQ * HD * 2;  // 4.2 MB
  u16* vn = (u16*)ws;    ws += (size_t)BB * NKV * SEQ * HD * 2;  // 4.2 MB
  u16* vt = (u16*)ws;    ws += (size_t)BB * NKV * SEQ * HD * 2;  // 4.2 MB
  u16* ao = (u16*)ws;    ws += (size_t)BB * SEQ * CH * 2;        // 16.8 MB

  xconv_kernel<<<dim3(BB * SEQ * CH / 1024), 256, 0, stream>>>(x, xb, BB * SEQ * CH / 4);
  wtrans4_kernel<<<dim3(32, 32, 4), 256, 0, stream>>>(Wq, Wk, Wv, Wo, wqkvt, wot);
  gemm_kernel<0><<<dim3(32, 24), 256, 0, stream>>>(xb, wqkvt, qkv, (float*)nullptr, vn,
                                                   bq, bk, bv, BB * SEQ, QKVC, CH);
  rope_kernel<<<dim3(BB * SEQ), 256, 0, stream>>>(qkv, pos, qr, kr);
  vtrans_kernel<<<dim3(SEQ / 64, HD / 64, BB * NKV), 256, 0, stream>>>(vn, vt);
  flash_kernel<<<dim3(8, NH, BB), 256, 0, stream>>>(qr, kr, vt, ao);
  gemm_kernel<1><<<dim3(32, 16), 256, 0, stream>>>(ao, wot, (u16*)nullptr, out, nullptr,
                                                   nullptr, nullptr, nullptr, BB * SEQ, CH, CH);
}

// Round 7
// 311.322 us; speedup vs baseline: 1.3828x; 1.3828x over previous
//
#include <hip/hip_runtime.h>
#include <cstdint>
#include <type_traits>

typedef unsigned short u16;
typedef unsigned int u32;
typedef __bf16 bf16x8 __attribute__((ext_vector_type(8)));
typedef float f32x4 __attribute__((ext_vector_type(4)));

constexpr int BB = 2;
constexpr int SEQ = 2048;
constexpr int CH = 2048;
constexpr int NH = 16;
constexpr int NKV = 4;
constexpr int HD = 128;
constexpr int QKVC = CH + 2 * NKV * HD;  // 3072

#define DI __device__ __forceinline__

DI u16 f2b(float x) {  // fp32 -> bf16 bits, RNE
  u32 u = __float_as_uint(x);
  u = u + 0x7FFFu + ((u >> 16) & 1u);
  return (u16)(u >> 16);
}
DI float b2f(u16 u) { return __uint_as_float(((u32)u) << 16); }

// pack two fp32 -> two bf16 (truncating) in ONE v_perm_b32
DI u32 pack2bf(float lo, float hi) {
  return __builtin_amdgcn_perm(__float_as_uint(hi), __float_as_uint(lo), 0x07060302u);
}

// async global->LDS, 16B per lane. LDS dest is wave-uniform base + lane*16.
DI void glds16(const void* g, void* l) {
  __builtin_amdgcn_global_load_lds(
      (__attribute__((address_space(1))) void*)(uintptr_t)g,
      (__attribute__((address_space(3))) void*)(u32)(uintptr_t)l, 16, 0, 0);
}

// ---------------- elementwise fp32 -> bf16 ----------------
__global__ __launch_bounds__(256) void xconv_kernel(const float* __restrict__ in,
                                                    u16* __restrict__ out, int n4) {
  int i = blockIdx.x * 256 + threadIdx.x;
  if (i < n4) {
    float4 v = *(const float4*)&in[(size_t)i * 4];
    ushort4 o;
    o.x = f2b(v.x); o.y = f2b(v.y); o.z = f2b(v.z); o.w = f2b(v.w);
    *(ushort4*)&out[(size_t)i * 4] = o;
  }
}

// ------- transpose-convert all 4 weights fp32 (2048 x Cc) -> bf16 (Cc x 2048) -------
__global__ __launch_bounds__(256) void wtrans4_kernel(
    const float* __restrict__ Wq, const float* __restrict__ Wk,
    const float* __restrict__ Wv, const float* __restrict__ Wo,
    u16* __restrict__ wqkvt, u16* __restrict__ wot) {
  const int z = blockIdx.z;
  const float* in;
  u16* out;
  int Cc;
  if (z == 0)      { in = Wq; out = wqkvt;                                Cc = CH; }
  else if (z == 1) { in = Wk; out = wqkvt + (size_t)CH * CH;              Cc = NKV * HD; }
  else if (z == 2) { in = Wv; out = wqkvt + (size_t)(CH + NKV * HD) * CH; Cc = NKV * HD; }
  else             { in = Wo; out = wot;                                  Cc = CH; }
  if ((int)blockIdx.y * 64 >= Cc) return;

  __shared__ u16 tile[64 * 65];
  const int r0 = blockIdx.x * 64, c0 = blockIdx.y * 64;
  const int tid = threadIdx.x;
  for (int c = tid; c < 1024; c += 256) {
    int r = c >> 4, col = (c & 15) * 4;
    float4 v = *(const float4*)&in[(size_t)(r0 + r) * Cc + c0 + col];
    tile[r * 65 + col + 0] = f2b(v.x);
    tile[r * 65 + col + 1] = f2b(v.y);
    tile[r * 65 + col + 2] = f2b(v.z);
    tile[r * 65 + col + 3] = f2b(v.w);
  }
  __syncthreads();
  for (int c = tid; c < 1024; c += 256) {
    int r = c >> 4, col = (c & 15) * 4;
    ushort4 v;
    v.x = tile[(col + 0) * 65 + r];
    v.y = tile[(col + 1) * 65 + r];
    v.z = tile[(col + 2) * 65 + r];
    v.w = tile[(col + 3) * 65 + r];
    *(ushort4*)&out[(size_t)(c0 + r) * CH + r0 + col] = v;
  }
}

// ------------- transpose bf16 V (SEQ x HD slices) -> V^T (HD x SEQ) -------------
// With flash-LDS kv-slot bit-permutation (w0..w5 = u0,u1,u5,u2,u3,u4) and
// XOR-16B-group swizzle (gl ^= d&7) folded into the output layout.
__global__ __launch_bounds__(256) void vtrans_kernel(const u16* __restrict__ in,
                                                     u16* __restrict__ out) {
  __shared__ u16 tile[64 * 65];
  const int s = blockIdx.z, n0 = blockIdx.x * 64, d0 = blockIdx.y * 64;
  const int tid = threadIdx.x;
  const u16* ip = in + (size_t)s * SEQ * HD + (size_t)n0 * HD + d0;
  u16* op = out + (size_t)s * HD * SEQ + (size_t)d0 * SEQ + n0;
  for (int c = tid; c < 1024; c += 256) {
    int r = c >> 4, col = (c & 15) * 4;
    ushort4 v = *(const ushort4*)&ip[(size_t)r * HD + col];
    tile[r * 65 + col + 0] = v.x;
    tile[r * 65 + col + 1] = v.y;
    tile[r * 65 + col + 2] = v.z;
    tile[r * 65 + col + 3] = v.w;
  }
  __syncthreads();
  for (int c = tid; c < 1024; c += 256) {
    int r = c >> 4, col = (c & 15) * 4;  // r = local d, col = local n (u), u&3==0
    ushort4 v;
    v.x = tile[(col + 0) * 65 + r];
    v.y = tile[(col + 1) * 65 + r];
    v.z = tile[(col + 2) * 65 + r];
    v.w = tile[(col + 3) * 65 + r];
    int u = col;
    int w = (u & 3) | (((u >> 5) & 1) << 2) | (((u >> 2) & 3) << 3) | (((u >> 4) & 1) << 5);
    int glp = (w >> 3) ^ (r & 7);
    int colp = glp * 8 + (w & 7);
    *(ushort4*)&op[(size_t)r * SEQ + colp] = v;
  }
}

// ---------------- bf16 MFMA GEMM, BK=64 (32 MFMAs per barrier-pair) ----------------
// C[M,Nn] = A[M,K] @ Bt[Nn,K]^T.  MODE 0: bf16 out + qkv bias, V columns routed
// directly to Vn[(b,kv,n,d)]. MODE 1: fp32 out.
// LDS rows hold 64 cols (128 B); 16B slot s of row r holds global col-group
// s^(r&7) (XOR swizzle on the GLOBAL side -- glds16 LDS side must stay
// base+lane*16). Readers use slot (cg)^(lm&7) -> banks spread over all 8 groups.
template <int MODE>
__global__ __launch_bounds__(256, 3) void gemm_kernel(
    const u16* __restrict__ A, const u16* __restrict__ Bt,
    u16* __restrict__ Cb, float* __restrict__ Cf, u16* __restrict__ Vn,
    const float* __restrict__ bq, const float* __restrict__ bk,
    const float* __restrict__ bv, int M, int Nn, int K) {
  __shared__ u16 As[128 * 64];
  __shared__ u16 Bs[128 * 64];
  const int tid = threadIdx.x;
  const int lane = tid & 63, wave = tid >> 6;
  const int wrow = wave >> 1, wcol = wave & 1;  // 2x2 waves of 64x64
  const int m0 = blockIdx.x * 128, n0 = blockIdx.y * 128;
  const int lm = lane & 15, lq = lane >> 4;
  f32x4 acc[4][4] = {};

  const int grow = tid >> 3;                          // staging row 0..31 (+c*32)
  const int gcol = ((lane & 7) ^ (lane >> 3)) * 8;    // swizzled global col
  const u16* ag = A + (size_t)(m0 + grow) * K + gcol;
  const u16* bg = Bt + (size_t)(n0 + grow) * K + gcol;
  char* asb = (char*)As + wave * 1024;  // wave-uniform LDS base (+c*4096)
  char* bsb = (char*)Bs + wave * 1024;
  const size_t rowskip = (size_t)32 * K;

  for (int k = 0; k < K; k += 64) {
    __syncthreads();
#pragma unroll
    for (int c = 0; c < 4; c++) {
      glds16(ag + c * rowskip + k, asb + c * 4096);
      glds16(bg + c * rowskip + k, bsb + c * 4096);
    }
    __syncthreads();  // vmcnt(0) drain -> tile staged
#pragma unroll
    for (int kk = 0; kk < 2; kk++) {
      bf16x8 af[4], bfr[4];
      const int slot = ((kk * 4 + lq) ^ (lm & 7)) * 16;
#pragma unroll
      for (int i = 0; i < 4; i++)
        af[i] = *(const bf16x8*)((const char*)As + (wrow * 64 + i * 16 + lm) * 128 + slot);
#pragma unroll
      for (int j = 0; j < 4; j++)
        bfr[j] = *(const bf16x8*)((const char*)Bs + (wcol * 64 + j * 16 + lm) * 128 + slot);
#pragma unroll
      for (int i = 0; i < 4; i++)
#pragma unroll
        for (int j = 0; j < 4; j++)
          acc[i][j] = __builtin_amdgcn_mfma_f32_16x16x32_bf16(af[i], bfr[j], acc[i][j], 0, 0, 0);
    }
  }

#pragma unroll
  for (int i = 0; i < 4; i++) {
    const int mg = m0 + wrow * 64 + i * 16 + lq * 4;
#pragma unroll
    for (int j = 0; j < 4; j++) {
      const int ng = n0 + wcol * 64 + j * 16 + lm;
      float bias = 0.f;
      if (MODE == 0)
        bias = (ng < CH) ? bq[ng] : (ng < CH + NKV * HD ? bk[ng - CH] : bv[ng - CH - NKV * HD]);
#pragma unroll
      for (int r = 0; r < 4; r++) {
        float v = acc[i][j][r] + bias;
        if (MODE == 0) {
          if (ng >= CH + NKV * HD) {  // V: route straight to (b,kv,n,d) layout
            int tok = mg + r;
            int bidx = tok >> 11, n = tok & (SEQ - 1);
            int vcol = ng - (CH + NKV * HD);
            int kh = vcol >> 7, d = vcol & (HD - 1);
            Vn[((size_t)(bidx * NKV + kh) * SEQ + n) * HD + d] = f2b(v);
          } else {
            Cb[(size_t)(mg + r) * Nn + ng] = f2b(v);
          }
        } else {
          Cf[(size_t)(mg + r) * Nn + ng] = v;
        }
      }
    }
  }
}

// ---------------- RoPE (interleaved), Q + K only ----------------
__global__ __launch_bounds__(256) void rope_kernel(
    const u16* __restrict__ qkv, const int* __restrict__ pos,
    u16* __restrict__ Qo, u16* __restrict__ Ko) {
  __shared__ float cs_s[64], sn_s[64];
  const int tok = blockIdx.x;
  const int b = tok >> 11, n = tok & (SEQ - 1);
  const int t = threadIdx.x;
  const u16* row = qkv + (size_t)tok * QKVC;
  const float LN1E4_64 = 0.14391156831212788f;  // ln(10000)/64

  if (t < 64) {
    float ang = (float)pos[tok] * expf(-(float)t * LN1E4_64);
    float sn, cs;
    sincosf(ang, &sn, &cs);
    cs_s[t] = cs;
    sn_s[t] = sn;
  }
  __syncthreads();

  for (int idx = t; idx < NH * 64; idx += 256) {  // q: 1024 pairs
    int hh = idx >> 6, i = idx & 63;
    float cs = cs_s[i], sn = sn_s[i];
    float q0v = b2f(row[hh * 128 + 2 * i]);
    float q1v = b2f(row[hh * 128 + 2 * i + 1]);
    size_t off = ((size_t)(b * NH + hh) * SEQ + n) * HD + 2 * i;
    Qo[off] = f2b(q0v * cs - q1v * sn);
    Qo[off + 1] = f2b(q1v * cs + q0v * sn);
  }
  {  // k: 256 pairs, one per thread, swizzled store
    int kh = t >> 6, i = t & 63;
    float cs = cs_s[i], sn = sn_s[i];
    float k0v = b2f(row[CH + kh * 128 + 2 * i]);
    float k1v = b2f(row[CH + kh * 128 + 2 * i + 1]);
    int d0 = 2 * i;
    int g = d0 >> 3;
    int gp = (g & 8) | ((g ^ n) & 7);
    int dp = gp * 8 + (d0 & 7);
    size_t off = ((size_t)(b * NKV + kh) * SEQ + n) * HD + dp;
    Ko[off] = f2b(k0v * cs - k1v * sn);
    Ko[off + 1] = f2b(k1v * cs + k0v * sn);
  }
}

// ---------------- causal GQA flash attention (v5: 2 paired q-tiles) ----------------
// Block p handles q-tiles {p, 31-p} (constant 33 work units). 512 blocks = 2/CU.
// VGPR-safe (124 regs, no spill) -- R6 showed 4 tiles/wave exceeds the 256
// addressable-VGPR cap and spills to scratch (254 MB writes). Keep 2 tiles.
//  * row-sums via MFMA ones-column (V^T LDS row 128 = bf16 ones)
//  * P pack via v_perm_b32 truncation
__global__ __launch_bounds__(256, 2) void flash_kernel(
    const u16* __restrict__ Q, const u16* __restrict__ Kk,
    const u16* __restrict__ Vt, u16* __restrict__ Oo) {
  __shared__ u16 Kb[2][64 * 128];    // [kv][d-swizzled]
  __shared__ u16 Vb[2][144 * 64];    // [d][kv-permuted-swizzled]; row 128 = ones
  const int tid = threadIdx.x, lane = tid & 63, wave = tid >> 6;
  const int lm = lane & 15, lq = lane >> 4;
  const int p = blockIdx.x;                  // pair index 0..15
  const int h = blockIdx.y, b = blockIdx.z;
  const int q0A = p * 64, q0B = (31 - p) * 64;
  const int kvh = h >> 2;  // groups = H/KV = 4
  const u16* Qg = Q + (size_t)(b * NH + h) * SEQ * HD;
  const u16* Kg = Kk + (size_t)(b * NKV + kvh) * SEQ * HD;
  const u16* Vg = Vt + (size_t)(b * NKV + kvh) * HD * SEQ;  // [HD][SEQ]

  if (tid < 128) Vb[tid >> 6][128 * 64 + (tid & 63)] = 0x3F80;  // bf16 1.0 ones-row

  // loop-invariant Q fragments (B-operand: lane holds Q[q=lm][k=lq*8+j])
  bf16x8 qf[2][4];
#pragma unroll
  for (int qg = 0; qg < 2; qg++) {
    const int q0g = qg ? q0B : q0A;
    const u16* qrow = Qg + (size_t)(q0g + wave * 16 + lm) * HD;
#pragma unroll
    for (int kd = 0; kd < 4; kd++)
      qf[qg][kd] = *(const bf16x8*)&qrow[kd * 32 + lq * 8];
  }

  f32x4 oacc[2][8] = {};
  f32x4 oaccS[2] = {};             // ones-column: row-sums of P
  const float SCL2 = 0.12754325f;  // (1/sqrt(128)) * log2(e)
  const int nIter = 32 - p;        // kv tiles needed by tile B

  // stage tile (64 kv) into buffer bufi: K 16KB contiguous, V 64-col slices
  auto stage = [&](int kv0, int bufi) {
    const char* kb = (const char*)(Kg + (size_t)kv0 * HD);
    char* kl = (char*)&Kb[bufi][0];
    const char* vbb = (const char*)(Vg + (size_t)kv0);
    char* vl = (char*)&Vb[bufi][0];
#pragma unroll
    for (int c = 0; c < 4; c++) {
      int ch = wave * 4 + c;
      glds16(kb + ch * 1024 + lane * 16, kl + ch * 1024);
      glds16(vbb + (size_t)(ch * 8 + (lane >> 3)) * (SEQ * 2) + (lane & 7) * 16,
             vl + ch * 1024);
    }
  };

  stage(0, 0);

  for (int t = 0; t < nIter; t++) {
    __syncthreads();                    // drains vmcnt -> tile t resident; closes reads of t-1
    if (t + 1 < nIter) stage((t + 1) * 64, (t + 1) & 1);  // async, hides behind compute
    const u16* Ks = &Kb[t & 1][0];
    const u16* Vs = &Vb[t & 1][0];
    const int kv0 = t * 64;
    const bool actA = (t <= p);  // tile A still needs this kv range

    auto run = [&](auto dualc) {
      constexpr bool DUAL = decltype(dualc)::value;
      // S^T tiles: lane holds S[q=lm][kv = nt*16 + lq*4 + r] per q-tile
      f32x4 sv[2][4] = {};
#pragma unroll
      for (int nt = 0; nt < 4; nt++)
#pragma unroll
        for (int kd = 0; kd < 4; kd++) {
          int g = kd * 4 + lq;
          int gpp = (g & 8) | ((g ^ lm) & 7);
          bf16x8 kf = *(const bf16x8*)&Ks[(nt * 16 + lm) * 128 + gpp * 8];
          sv[1][nt] = __builtin_amdgcn_mfma_f32_16x16x32_bf16(kf, qf[1][kd], sv[1][nt], 0, 0, 0);
          if constexpr (DUAL)
            sv[0][nt] = __builtin_amdgcn_mfma_f32_16x16x32_bf16(kf, qf[0][kd], sv[0][nt], 0, 0, 0);
        }

      // p = exp2(s*scale); perm-pack (truncate) into x32 A-frags:
      // element j=(nt>>1)*4+r of frag ks=nt&1  ->  dword (nt>>1)*2+(r>>1), half r&1
      alignas(16) u32 pad[2][2][4];  // [qg][ks][dword]
      auto softmax = [&](int qg, int q0g) {
        const int base = q0g + wave * 16;
        if (kv0 + 63 > base) {  // tile straddles diagonal for this q-tile
          const int qrow = base + lm;
#pragma unroll
          for (int nt = 0; nt < 4; nt++) {
            float pv[4];
#pragma unroll
            for (int r = 0; r < 4; r++) {
              int kvg = kv0 + nt * 16 + lq * 4 + r;
              float e = exp2f(sv[qg][nt][r] * SCL2);
              pv[r] = (kvg > qrow) ? 0.f : e;
            }
            pad[qg][nt & 1][(nt >> 1) * 2 + 0] = pack2bf(pv[0], pv[1]);
            pad[qg][nt & 1][(nt >> 1) * 2 + 1] = pack2bf(pv[2], pv[3]);
          }
        } else {
#pragma unroll
          for (int nt = 0; nt < 4; nt++) {
            float pv[4];
#pragma unroll
            for (int r = 0; r < 4; r++) pv[r] = exp2f(sv[qg][nt][r] * SCL2);
            pad[qg][nt & 1][(nt >> 1) * 2 + 0] = pack2bf(pv[0], pv[1]);
            pad[qg][nt & 1][(nt >> 1) * 2 + 1] = pack2bf(pv[2], pv[3]);
          }
        }
      };
      softmax(1, q0B);
      if constexpr (DUAL) softmax(0, q0A);

      // O += P.V  (x32; B-frag = V^T[d][kv] slots, pre-permuted+swizzled)
#pragma unroll
      for (int ks = 0; ks < 2; ks++) {
        const int glp = (ks * 4 + lq) ^ (lm & 7);
        const bf16x8 pa1 = *(const bf16x8*)&pad[1][ks][0];
        const bf16x8 pa0 = *(const bf16x8*)&pad[0][ks][0];
#pragma unroll
        for (int dt = 0; dt < 8; dt++) {
          bf16x8 vf = *(const bf16x8*)&Vs[(dt * 16 + lm) * 64 + glp * 8];
          oacc[1][dt] = __builtin_amdgcn_mfma_f32_16x16x32_bf16(pa1, vf, oacc[1][dt], 0, 0, 0);
          if constexpr (DUAL)
            oacc[0][dt] = __builtin_amdgcn_mfma_f32_16x16x32_bf16(pa0, vf, oacc[0][dt], 0, 0, 0);
        }
        // ones-column -> row sums (col d=128 lives at lane lm==0)
        bf16x8 vf8 = *(const bf16x8*)&Vs[(128 + lm) * 64 + glp * 8];
        oaccS[1] = __builtin_amdgcn_mfma_f32_16x16x32_bf16(pa1, vf8, oaccS[1], 0, 0, 0);
        if constexpr (DUAL)
          oaccS[0] = __builtin_amdgcn_mfma_f32_16x16x32_bf16(pa0, vf8, oaccS[0], 0, 0, 0);
      }
    };
    if (actA) run(std::integral_constant<bool, true>{});
    else      run(std::integral_constant<bool, false>{});
  }

  // row m's sum sits at lane (m>>2)*16, reg m&3 of oaccS (C-layout col 128 = lm 0)
  u16* orow = Oo + (size_t)b * SEQ * CH + (size_t)h * HD;
#pragma unroll
  for (int qg = 0; qg < 2; qg++) {
    const int q0g = qg ? q0B : q0A;
    float inv[4];
#pragma unroll
    for (int r = 0; r < 4; r++) inv[r] = 1.0f / __shfl(oaccS[qg][r], lq * 16);
    const int qrow_base = q0g + wave * 16 + lq * 4;
#pragma unroll
    for (int dt = 0; dt < 8; dt++)
#pragma unroll
      for (int r = 0; r < 4; r++)
        orow[(size_t)(qrow_base + r) * CH + dt * 16 + lm] = f2b(oacc[qg][dt][r] * inv[r]);
  }
}

extern "C" void kernel_launch(void* const* d_in, const int* in_sizes, int n_in,
                              void* d_out, int out_size, void* d_ws, size_t ws_size,
                              hipStream_t stream) {
  const float* x = (const float*)d_in[0];
  const int* pos = (const int*)d_in[1];
  const float* Wq = (const float*)d_in[2];
  const float* bq = (const float*)d_in[3];
  const float* Wk = (const float*)d_in[4];
  const float* bk = (const float*)d_in[5];
  const float* Wv = (const float*)d_in[6];
  const float* bv = (const float*)d_in[7];
  const float* Wo = (const float*)d_in[8];
  float* out = (float*)d_out;

  char* ws = (char*)d_ws;
  u16* xb = (u16*)ws;    ws += (size_t)BB * SEQ * CH * 2;        // 16.8 MB
  u16* wqkvt = (u16*)ws; ws += (size_t)QKVC * CH * 2;            // 12.6 MB  (3072 x 2048, n-major)
  u16* wot = (u16*)ws;   ws += (size_t)CH * CH * 2;              // 8.4 MB
  u16* qkv = (u16*)ws;   ws += (size_t)BB * SEQ * QKVC * 2;      // 25.2 MB
  u16* qr = (u16*)ws;    ws += (size_t)BB * NH * SEQ * HD * 2;   // 16.8 MB
  u16* kr = (u16*)ws;    ws += (size_t)BB * NKV * SEQ * HD * 2;  // 4.2 MB
  u16* vn = (u16*)ws;    ws += (size_t)BB * NKV * SEQ * HD * 2;  // 4.2 MB
  u16* vt = (u16*)ws;    ws += (size_t)BB * NKV * SEQ * HD * 2;  // 4.2 MB
  u16* ao = (u16*)ws;    ws += (size_t)BB * SEQ * CH * 2;        // 16.8 MB

  xconv_kernel<<<dim3(BB * SEQ * CH / 1024), 256, 0, stream>>>(x, xb, BB * SEQ * CH / 4);
  wtrans4_kernel<<<dim3(32, 32, 4), 256, 0, stream>>>(Wq, Wk, Wv, Wo, wqkvt, wot);
  gemm_kernel<0><<<dim3(32, 24), 256, 0, stream>>>(xb, wqkvt, qkv, (float*)nullptr, vn,
                                                   bq, bk, bv, BB * SEQ, QKVC, CH);
  rope_kernel<<<dim3(BB * SEQ), 256, 0, stream>>>(qkv, pos, qr, kr);
  vtrans_kernel<<<dim3(SEQ / 64, HD / 64, BB * NKV), 256, 0, stream>>>(vn, vt);
  flash_kernel<<<dim3(16, NH, BB), 256, 0, stream>>>(qr, kr, vt, ao);
  gemm_kernel<1><<<dim3(32, 16), 256, 0, stream>>>(ao, wot, (u16*)nullptr, out, nullptr,
                                                   nullptr, nullptr, nullptr, BB * SEQ, CH, CH);
}